// Round 6
// baseline (274.516 us; speedup 1.0000x reference)
//
#include <hip/hip_runtime.h>

#define F 256
#define TWO_F 512

typedef __attribute__((ext_vector_type(8))) short short8;
typedef __attribute__((ext_vector_type(4))) float float4v;

// ---------- bf16 helpers ----------
static __device__ __forceinline__ unsigned short f2bf(float f) {
    unsigned u = __float_as_uint(f);
    u += 0x7FFFu + ((u >> 16) & 1u);
    return (unsigned short)(u >> 16);
}
// pack two floats -> two bf16 (round-half-up) in 2 adds + 1 v_perm
static __device__ __forceinline__ unsigned pack2(float lo, float hi) {
    unsigned a = __float_as_uint(lo) + 0x8000u;
    unsigned b = __float_as_uint(hi) + 0x8000u;
    return __builtin_amdgcn_perm(b, a, 0x07060302u);
}
static __device__ __forceinline__ float blo(unsigned u) { return __uint_as_float(u << 16); }
static __device__ __forceinline__ float rawf(unsigned u) { return __uint_as_float(u); }

// ---------- kernel 1: W1 fp32 [256][512] -> Wb bf16 [n][k], plain transpose (no swizzle) ----------
__global__ void prep_w_kernel(const float* __restrict__ W1, unsigned short* __restrict__ Wb) {
    int i = blockIdx.x * blockDim.x + threadIdx.x;
    if (i >= TWO_F * F) return;
    int n = i >> 8;
    int k = i & 255;
    Wb[i] = f2bf(W1[(n & 255) * TWO_F + ((n >> 8) << 8) + k]);
}

// ---------- kernel 2: barrier-free GEMM. B strip in registers, A streamed fp32->bf16. ----------
// Block = 4 waves; wave w owns n-strip [by*256 + w*64, +64); block owns 128 m-rows (8 tiles of 16).
// No LDS, no __syncthreads -- latency hidden by vmcnt ILP + occupancy.
__global__ __launch_bounds__(256, 2) void gemm_kernel(
    const float* __restrict__ h, const unsigned short* __restrict__ Wb,
    const float* __restrict__ b1v, unsigned short* __restrict__ C, int M)
{
    const int tid  = threadIdx.x;
    const int lane = tid & 63;
    const int wv   = tid >> 6;
    const int quad = lane >> 4;
    const int l15  = lane & 15;

    // XCD pairing: the two by-blocks of one m-chunk land on the same (ib&7) slot -> same XCD,
    // so the 8 wave-strips re-reading the same A rows hit L2.
    const int ib = blockIdx.x;
    const int mchunk = (ib >> 4) * 8 + (ib & 7);
    const int by = (ib >> 3) & 1;
    const int m0 = mchunk * 128;
    if (m0 >= M) return;
    const int nbase = by * 256 + wv * 64;

    // --- B frags: n-strip 64 x K 256 = 128 VGPR, loaded once (Wb is L2-hot, 256 KB) ---
    short8 bfr[4][8];
    #pragma unroll
    for (int nt = 0; nt < 4; ++nt) {
        const unsigned short* bp = Wb + (size_t)(nbase + nt * 16 + l15) * F + quad * 8;
        #pragma unroll
        for (int ks = 0; ks < 8; ++ks)
            bfr[nt][ks] = *(const short8*)(bp + ks * 32);
    }

    float bias[4];
    #pragma unroll
    for (int nt = 0; nt < 4; ++nt)
        bias[nt] = (by == 0) ? b1v[nbase + nt * 16 + l15] : 0.f;

    // --- m-loop: 8 tiles of 16 rows ---
    for (int t = 0; t < 8; ++t) {
        const int mt0 = m0 + t * 16;
        int arow = mt0 + l15; if (arow > M - 1) arow = M - 1;   // clamp; stores guarded
        const float* ap = h + (size_t)arow * F + quad * 8;

        float4v acc[4];
        acc[0] = acc[1] = acc[2] = acc[3] = (float4v)(0.f);

        #pragma unroll
        for (int ks = 0; ks < 8; ++ks) {
            float4 lo = *(const float4*)(ap + ks * 32);
            float4 hi = *(const float4*)(ap + ks * 32 + 4);
            union { unsigned u[4]; short8 s; } a;
            a.u[0] = pack2(lo.x, lo.y);
            a.u[1] = pack2(lo.z, lo.w);
            a.u[2] = pack2(hi.x, hi.y);
            a.u[3] = pack2(hi.z, hi.w);
            #pragma unroll
            for (int nt = 0; nt < 4; ++nt)
                acc[nt] = __builtin_amdgcn_mfma_f32_16x16x32_bf16(
                    a.s, bfr[nt][ks], acc[nt], 0, 0, 0);
        }

        // epilogue: C/D layout col=l15, row=quad*4+reg; +b1 on the n<256 half
        #pragma unroll
        for (int r = 0; r < 4; ++r) {
            int gm = mt0 + quad * 4 + r;
            if (gm < M) {
                unsigned short* cp = C + (size_t)gm * TWO_F + nbase + l15;
                #pragma unroll
                for (int nt = 0; nt < 4; ++nt)
                    cp[nt * 16] = f2bf(acc[nt][r] + bias[nt]);
            }
        }
    }
}

// ---------- kernel 3: per-edge score, 2 edges per 32-lane group (R4's best variant) ----------
__global__ __launch_bounds__(256) void edge_kernel(
    const unsigned short* __restrict__ C,
    const int* __restrict__ src, const int* __restrict__ dst,
    const float* __restrict__ w2,
    const float* __restrict__ b2, float* __restrict__ out, int E)
{
    const int lane = threadIdx.x & 31;
    const int g = blockIdx.x * 8 + (threadIdx.x >> 5);
    const int e0 = g * 2;
    if (e0 >= E) return;
    const int s0 = src[e0], d0 = dst[e0];
    const int s1 = src[e0 + 1], d1 = dst[e0 + 1];

    uint4 av0 = *(const uint4*)(C + (size_t)s0 * TWO_F + lane * 8);
    uint4 bv0 = *(const uint4*)(C + (size_t)d0 * TWO_F + F + lane * 8);
    uint4 av1 = *(const uint4*)(C + (size_t)s1 * TWO_F + lane * 8);
    uint4 bv1 = *(const uint4*)(C + (size_t)d1 * TWO_F + F + lane * 8);
    float4 w0 = *(const float4*)(w2 + lane * 8);
    float4 w1 = *(const float4*)(w2 + lane * 8 + 4);

    float sum0, sum1;
    sum0  = w0.x * fmaxf(blo(av0.x) + blo(bv0.x), 0.f);
    sum0 += w0.y * fmaxf(rawf(av0.x) + rawf(bv0.x), 0.f);
    sum0 += w0.z * fmaxf(blo(av0.y) + blo(bv0.y), 0.f);
    sum0 += w0.w * fmaxf(rawf(av0.y) + rawf(bv0.y), 0.f);
    sum0 += w1.x * fmaxf(blo(av0.z) + blo(bv0.z), 0.f);
    sum0 += w1.y * fmaxf(rawf(av0.z) + rawf(bv0.z), 0.f);
    sum0 += w1.z * fmaxf(blo(av0.w) + blo(bv0.w), 0.f);
    sum0 += w1.w * fmaxf(rawf(av0.w) + rawf(bv0.w), 0.f);

    sum1  = w0.x * fmaxf(blo(av1.x) + blo(bv1.x), 0.f);
    sum1 += w0.y * fmaxf(rawf(av1.x) + rawf(bv1.x), 0.f);
    sum1 += w0.z * fmaxf(blo(av1.y) + blo(bv1.y), 0.f);
    sum1 += w0.w * fmaxf(rawf(av1.y) + rawf(bv1.y), 0.f);
    sum1 += w1.x * fmaxf(blo(av1.z) + blo(bv1.z), 0.f);
    sum1 += w1.y * fmaxf(rawf(av1.z) + rawf(bv1.z), 0.f);
    sum1 += w1.z * fmaxf(blo(av1.w) + blo(bv1.w), 0.f);
    sum1 += w1.w * fmaxf(rawf(av1.w) + rawf(bv1.w), 0.f);

    #pragma unroll
    for (int off = 16; off > 0; off >>= 1) {
        sum0 += __shfl_down(sum0, off, 32);
        sum1 += __shfl_down(sum1, off, 32);
    }

    if (lane == 0) {
        float b = b2[0];
        out[e0]     = sum0 + b;
        out[e0 + 1] = sum1 + b;
    }
}

extern "C" void kernel_launch(void* const* d_in, const int* in_sizes, int n_in,
                              void* d_out, int out_size, void* d_ws, size_t ws_size,
                              hipStream_t stream) {
    const float* h    = (const float*)d_in[0];
    const int*   src  = (const int*)d_in[1];
    const int*   dst  = (const int*)d_in[2];
    const float* W1_w = (const float*)d_in[3];
    const float* W1_b = (const float*)d_in[4];
    const float* W2_w = (const float*)d_in[5];
    const float* W2_b = (const float*)d_in[6];
    float* out = (float*)d_out;

    const int M = in_sizes[0] / F;   // 50000
    const int E = in_sizes[1];       // 800000

    // ws: [Wb bf16 256KB][pad to 512KB][C bf16 ~51.2MB]
    unsigned short* Wb = (unsigned short*)d_ws;
    unsigned short* C  = (unsigned short*)((char*)d_ws + 512 * 1024);

    prep_w_kernel<<<(TWO_F * F + 255) / 256, 256, 0, stream>>>(W1_w, Wb);

    // grid: 392 m-chunks (of 128 rows) x 2 n-halves, XCD-paired encoding
    int nchunks = ((M + 127) / 128 + 7) / 8 * 8;   // 392
    gemm_kernel<<<nchunks * 2, 256, 0, stream>>>(h, Wb, W1_b, C, M);

    edge_kernel<<<(E / 2 + 7) / 8, 256, 0, stream>>>(C, src, dst, W2_w, W2_b, out, E);
}

// Round 7
// 226.693 us; speedup vs baseline: 1.2110x; 1.2110x over previous
//
#include <hip/hip_runtime.h>

#define F 256
#define TWO_F 512
#define BM 128
#define BN 64
#define BK 64

typedef __attribute__((ext_vector_type(8))) short short8;
typedef __attribute__((ext_vector_type(4))) float float4v;

// ---------- bf16 helpers ----------
static __device__ __forceinline__ unsigned short f2bf(float f) {
    unsigned u = __float_as_uint(f);
    u += 0x7FFFu + ((u >> 16) & 1u);
    return (unsigned short)(u >> 16);
}
// pack two floats -> two bf16 (round-half-up) in 2 adds + 1 v_perm
static __device__ __forceinline__ unsigned pack2(float lo, float hi) {
    unsigned a = __float_as_uint(lo) + 0x8000u;
    unsigned b = __float_as_uint(hi) + 0x8000u;
    return __builtin_amdgcn_perm(b, a, 0x07060302u);
}
static __device__ __forceinline__ float blo(unsigned u) { return __uint_as_float(u << 16); }
static __device__ __forceinline__ float rawf(unsigned u) { return __uint_as_float(u); }

// ---------- kernel 1 (merged prep): h fp32->hb bf16 and W1 fp32->Wb bf16, both k-rotated ----------
// rotation: within each 64-elem k-block, elem k -> (k + (row&7)*8) & 63  (row = m for hb, n for Wb)
__global__ __launch_bounds__(256) void prep_kernel(
    const float* __restrict__ h, const float* __restrict__ W1,
    unsigned short* __restrict__ hb, unsigned short* __restrict__ Wb, int M)
{
    int i = blockIdx.x * blockDim.x + threadIdx.x;
    if (i < M * 128) {                       // h part: one bf16 pair per thread
        int m = i >> 7;
        int kp = (i & 127) * 2;
        float2 v = *(const float2*)(h + (size_t)m * F + kp);
        unsigned pk = pack2(v.x, v.y);
        int ksw = ((kp & 63) + (m & 7) * 8) & 63;   // rotation multiple of 8 -> pair intact
        *(unsigned*)(hb + (size_t)m * F + (kp & ~63) + ksw) = pk;
    }
    if (i < TWO_F * F) {                     // W part: one elem per thread (first 512 blocks)
        int n = i >> 8;
        int k = i & 255;
        float v = W1[(n & 255) * TWO_F + ((n >> 8) << 8) + k];
        int kin_sw = ((k & 63) + (n & 7) * 8) & 63;
        Wb[n * F + (k & ~63) + kin_sw] = f2bf(v);
    }
}

// ---------- kernel 2: C[m][n] = sum_k hb[m][k]*Wb[n][k] (+b1 for n<256), bf16 out ----------
// BM=128 x BN=64, 24 KB LDS, 4 blocks/CU. Wave self-stages its own 32 m-rows of sA.
__global__ __launch_bounds__(256, 4) void gemm_kernel(
    const unsigned short* __restrict__ hb, const unsigned short* __restrict__ Wb,
    const float* __restrict__ b1v, unsigned short* __restrict__ C, int M)
{
    __shared__ unsigned short sA[BM * BK];   // 16 KB
    __shared__ unsigned short sB[BN * BK];   //  8 KB

    // XCD pairing: all 8 by-blocks of one bx share (ib&7) -> same XCD -> h strip L2-reused 8x.
    const int ib = blockIdx.x;
    const int r8 = ib & 7;
    const int q  = ib >> 3;
    const int by = q & 7;
    const int bx = (q >> 3) * 8 + r8;
    const int bm = bx * BM;
    if (bm >= M) return;
    const int bn = by * BN;

    const int tid  = threadIdx.x;
    const int lane = tid & 63;
    const int wid  = tid >> 6;
    const int st_r = lane >> 3;
    const int st_k = (lane & 7) * 8;
    const int quad = lane >> 4;
    const int l15  = lane & 15;
    const int rot  = (l15 & 7) * 8;

    float4v acc[2][4];
    #pragma unroll
    for (int i = 0; i < 2; ++i)
        #pragma unroll
        for (int j = 0; j < 4; ++j) acc[i][j] = (float4v)(0.f);

    for (int k0 = 0; k0 < F; k0 += BK) {
        // sA: wave stages its own m-strip rows wid*32 .. +31 (4 issues x 8 rows)
        #pragma unroll
        for (int p = 0; p < 4; ++p) {
            int r = wid * 32 + p * 8;
            int am = bm + r + st_r; if (am > M - 1) am = M - 1;   // clamp; stores guarded
            const unsigned short* ga = hb + (size_t)am * F + k0 + st_k;
            __builtin_amdgcn_global_load_lds(
                (const __attribute__((address_space(1))) unsigned int*)ga,
                (__attribute__((address_space(3))) unsigned int*)&sA[r * BK],
                16, 0, 0);
        }
        // sB: wave stages rows wid*16 .. +15 (2 issues x 8 rows)
        #pragma unroll
        for (int p = 0; p < 2; ++p) {
            int r = wid * 16 + p * 8;
            const unsigned short* gb = Wb + (size_t)(bn + r + st_r) * F + k0 + st_k;
            __builtin_amdgcn_global_load_lds(
                (const __attribute__((address_space(1))) unsigned int*)gb,
                (__attribute__((address_space(3))) unsigned int*)&sB[r * BK],
                16, 0, 0);
        }
        __syncthreads();

        #pragma unroll
        for (int ks = 0; ks < 2; ++ks) {
            const int koff = (ks * 32 + quad * 8 + rot) & 63;
            short8 afr[2], bfr[4];
            #pragma unroll
            for (int mt = 0; mt < 2; ++mt)
                afr[mt] = *(const short8*)&sA[(wid * 32 + mt * 16 + l15) * BK + koff];
            #pragma unroll
            for (int nt = 0; nt < 4; ++nt)
                bfr[nt] = *(const short8*)&sB[(nt * 16 + l15) * BK + koff];
            #pragma unroll
            for (int mt = 0; mt < 2; ++mt)
                #pragma unroll
                for (int nt = 0; nt < 4; ++nt)
                    acc[mt][nt] = __builtin_amdgcn_mfma_f32_16x16x32_bf16(
                        afr[mt], bfr[nt], acc[mt][nt], 0, 0, 0);
        }
        __syncthreads();
    }

    // epilogue: +b1 for the n<256 half, bf16 store
    float bias[4];
    #pragma unroll
    for (int nt = 0; nt < 4; ++nt) {
        int n = bn + nt * 16 + l15;
        bias[nt] = (n < F) ? b1v[n] : 0.f;
    }
    #pragma unroll
    for (int mt = 0; mt < 2; ++mt) {
        int gm0 = bm + wid * 32 + mt * 16 + quad * 4;
        #pragma unroll
        for (int rr = 0; rr < 4; ++rr) {
            int gm = gm0 + rr;
            if (gm < M) {
                unsigned short* cp = C + (size_t)gm * TWO_F + bn + l15;
                #pragma unroll
                for (int nt = 0; nt < 4; ++nt)
                    cp[nt * 16] = f2bf(acc[mt][nt][rr] + bias[nt]);
            }
        }
    }
}

// ---------- kernel 3: per-edge score, 2 edges per 32-lane group (R4's best variant) ----------
__global__ __launch_bounds__(256) void edge_kernel(
    const unsigned short* __restrict__ C,
    const int* __restrict__ src, const int* __restrict__ dst,
    const float* __restrict__ w2,
    const float* __restrict__ b2, float* __restrict__ out, int E)
{
    const int lane = threadIdx.x & 31;
    const int g = blockIdx.x * 8 + (threadIdx.x >> 5);
    const int e0 = g * 2;
    if (e0 >= E) return;
    const int s0 = src[e0], d0 = dst[e0];
    const int s1 = src[e0 + 1], d1 = dst[e0 + 1];

    uint4 av0 = *(const uint4*)(C + (size_t)s0 * TWO_F + lane * 8);
    uint4 bv0 = *(const uint4*)(C + (size_t)d0 * TWO_F + F + lane * 8);
    uint4 av1 = *(const uint4*)(C + (size_t)s1 * TWO_F + lane * 8);
    uint4 bv1 = *(const uint4*)(C + (size_t)d1 * TWO_F + F + lane * 8);
    float4 w0 = *(const float4*)(w2 + lane * 8);
    float4 w1 = *(const float4*)(w2 + lane * 8 + 4);

    float sum0, sum1;
    sum0  = w0.x * fmaxf(blo(av0.x) + blo(bv0.x), 0.f);
    sum0 += w0.y * fmaxf(rawf(av0.x) + rawf(bv0.x), 0.f);
    sum0 += w0.z * fmaxf(blo(av0.y) + blo(bv0.y), 0.f);
    sum0 += w0.w * fmaxf(rawf(av0.y) + rawf(bv0.y), 0.f);
    sum0 += w1.x * fmaxf(blo(av0.z) + blo(bv0.z), 0.f);
    sum0 += w1.y * fmaxf(rawf(av0.z) + rawf(bv0.z), 0.f);
    sum0 += w1.z * fmaxf(blo(av0.w) + blo(bv0.w), 0.f);
    sum0 += w1.w * fmaxf(rawf(av0.w) + rawf(bv0.w), 0.f);

    sum1  = w0.x * fmaxf(blo(av1.x) + blo(bv1.x), 0.f);
    sum1 += w0.y * fmaxf(rawf(av1.x) + rawf(bv1.x), 0.f);
    sum1 += w0.z * fmaxf(blo(av1.y) + blo(bv1.y), 0.f);
    sum1 += w0.w * fmaxf(rawf(av1.y) + rawf(bv1.y), 0.f);
    sum1 += w1.x * fmaxf(blo(av1.z) + blo(bv1.z), 0.f);
    sum1 += w1.y * fmaxf(rawf(av1.z) + rawf(bv1.z), 0.f);
    sum1 += w1.z * fmaxf(blo(av1.w) + blo(bv1.w), 0.f);
    sum1 += w1.w * fmaxf(rawf(av1.w) + rawf(bv1.w), 0.f);

    #pragma unroll
    for (int off = 16; off > 0; off >>= 1) {
        sum0 += __shfl_down(sum0, off, 32);
        sum1 += __shfl_down(sum1, off, 32);
    }

    if (lane == 0) {
        float b = b2[0];
        out[e0]     = sum0 + b;
        out[e0 + 1] = sum1 + b;
    }
}

extern "C" void kernel_launch(void* const* d_in, const int* in_sizes, int n_in,
                              void* d_out, int out_size, void* d_ws, size_t ws_size,
                              hipStream_t stream) {
    const float* h    = (const float*)d_in[0];
    const int*   src  = (const int*)d_in[1];
    const int*   dst  = (const int*)d_in[2];
    const float* W1_w = (const float*)d_in[3];
    const float* W1_b = (const float*)d_in[4];
    const float* W2_w = (const float*)d_in[5];
    const float* W2_b = (const float*)d_in[6];
    float* out = (float*)d_out;

    const int M = in_sizes[0] / F;   // 50000
    const int E = in_sizes[1];       // 800000

    // ws: [Wb bf16 256KB][pad to 512KB][hb bf16 25.6MB, pad to 26MB][C bf16 51.2MB]
    unsigned short* Wb = (unsigned short*)d_ws;
    unsigned short* hb = (unsigned short*)((char*)d_ws + 512 * 1024);
    unsigned short* C  = (unsigned short*)((char*)d_ws + 512 * 1024 + 26 * 1024 * 1024);

    // merged prep: grid covers both h pairs (M*128 threads) and W elems (131072 threads)
    int prep_threads = M * 128 > TWO_F * F ? M * 128 : TWO_F * F;
    prep_kernel<<<(prep_threads + 255) / 256, 256, 0, stream>>>(h, W1_w, hb, Wb, M);

    // grid: 392 m-chunks x 8 n-blocks, XCD-paired encoding
    int nbx = ((M + BM - 1) / BM + 7) / 8 * 8;     // 392
    gemm_kernel<<<nbx * 8, 256, 0, stream>>>(hb, Wb, W1_b, C, M);

    edge_kernel<<<(E / 2 + 7) / 8, 256, 0, stream>>>(C, src, dst, W2_w, W2_b, out, E);
}